// Round 3
// baseline (270.903 us; speedup 1.0000x reference)
//
#include <hip/hip_runtime.h>

typedef __bf16 bf16;
typedef __bf16 bf16x8 __attribute__((ext_vector_type(8)));
typedef float f32x4 __attribute__((ext_vector_type(4)));

#define NN 8192

__device__ inline bf16x8 cvt8(float4 lo, float4 hi) {
  bf16x8 r;
  r[0] = (__bf16)lo.x; r[1] = (__bf16)lo.y; r[2] = (__bf16)lo.z; r[3] = (__bf16)lo.w;
  r[4] = (__bf16)hi.x; r[5] = (__bf16)hi.y; r[6] = (__bf16)hi.z; r[7] = (__bf16)hi.w;
  return r;
}

// ---------------- enc1: B1p[k/32][c(128)][k&31] = relu(nodes @ We1 + be1) packed bf16
// 32-row tiles -> 256 blocks.
__global__ __launch_bounds__(256) void k_enc1(const float* __restrict__ nodes,
                                              const float* __restrict__ We1,
                                              const float* __restrict__ be1,
                                              bf16* __restrict__ B1p) {
  __shared__ float Ns[32 * 68];
  __shared__ bf16 Os[128 * 40];   // [col][32 rows], stride 40 (80B, uint4-aligned)
  int tid = threadIdx.x;
  int r0 = blockIdx.x * 32;
  for (int idx = tid; idx < 512; idx += 256) {
    int r = idx >> 4, c4 = (idx & 15) * 4;
    *(float4*)(&Ns[r * 68 + c4]) = *(const float4*)(nodes + (r0 + r) * 64 + c4);
  }
  __syncthreads();
  int c = tid & 127, rb = tid >> 7;  // rows rb + 2k, k<16
  float acc[16];
  float b = be1[c];
#pragma unroll
  for (int k = 0; k < 16; ++k) acc[k] = b;
  for (int f = 0; f < 64; ++f) {
    float wv = We1[f * 128 + c];
#pragma unroll
    for (int k = 0; k < 16; ++k)
      acc[k] = fmaf(Ns[(rb + 2 * k) * 68 + f], wv, acc[k]);
  }
#pragma unroll
  for (int k = 0; k < 16; ++k) {
    float v = acc[k] > 0.f ? acc[k] : 0.f;
    Os[c * 40 + rb + 2 * k] = (bf16)v;
  }
  __syncthreads();
  int c2 = tid >> 1, h = tid & 1;  // 2 threads/col, 32B each
  const uint4* src = (const uint4*)(Os + c2 * 40 + h * 16);
  uint4* dst = (uint4*)(B1p + (size_t)(r0 / 32) * 128 * 32 + c2 * 32 + h * 16);
  dst[0] = src[0]; dst[1] = src[1];
}

// ---------------- pass: Out[part][r][c] = A[:, krange] @ Bpacked, no LDS, no barriers.
// Block: 64 rows x (2*NCG*16) cols; 4 waves = 2 rowg x 2 colg; wave = 32 rows x NCG*16 cols.
// A and B both double-buffered one 32-k step ahead.
struct AF { float4 q[4]; };

template <int NCG>
__global__ __launch_bounds__(256, 4) void k_pass(const float* __restrict__ A,
                                                 const bf16* __restrict__ Bp,
                                                 float* __restrict__ Out,
                                                 int KL) {
  constexpr int COLS = 2 * NCG * 16;
  int tid = threadIdx.x;
  int lane = tid & 63, w = tid >> 6;
  int rowg = w >> 1, colg = w & 1;
  int l15 = lane & 15, lg = lane >> 4;
  int klane = lg * 8;
  int r0 = blockIdx.x * 64 + rowg * 32;
  int kbase = blockIdx.y * KL;
  const float* pa0 = A + (size_t)(r0 + l15) * NN + kbase + klane;
  const float* pa1 = pa0 + (size_t)16 * NN;
  const bf16* bbase = Bp + ((size_t)(kbase >> 5) * COLS + colg * (NCG * 16) + l15) * 32 + klane;

  f32x4 acc[2][NCG];
#pragma unroll
  for (int m = 0; m < 2; ++m)
#pragma unroll
    for (int cg = 0; cg < NCG; ++cg) acc[m][cg] = (f32x4){0.f, 0.f, 0.f, 0.f};

  auto LDA = [&](int kt, AF& f) {
    f.q[0] = *(const float4*)(pa0 + kt);
    f.q[1] = *(const float4*)(pa0 + kt + 4);
    f.q[2] = *(const float4*)(pa1 + kt);
    f.q[3] = *(const float4*)(pa1 + kt + 4);
  };
  auto LDB = [&](int kt, uint4* b) {
    const bf16* p = bbase + (size_t)(kt >> 5) * (COLS * 32);
#pragma unroll
    for (int cg = 0; cg < NCG; ++cg) b[cg] = *(const uint4*)(p + cg * 512);
  };
  auto CMP = [&](const AF& f, const uint4* b) {
    bf16x8 a0 = cvt8(f.q[0], f.q[1]);
    bf16x8 a1 = cvt8(f.q[2], f.q[3]);
#pragma unroll
    for (int cg = 0; cg < NCG; ++cg) {
      bf16x8 bfr = __builtin_bit_cast(bf16x8, b[cg]);
      acc[0][cg] = __builtin_amdgcn_mfma_f32_16x16x32_bf16(a0, bfr, acc[0][cg], 0, 0, 0);
      acc[1][cg] = __builtin_amdgcn_mfma_f32_16x16x32_bf16(a1, bfr, acc[1][cg], 0, 0, 0);
    }
  };

  AF a0f, a1f;
  uint4 b0[NCG], b1[NCG];
  LDA(0, a0f);
  LDB(0, b0);
  int ktail = KL - 64;
  int kt = 0;
  for (; kt < ktail; kt += 64) {
    LDA(kt + 32, a1f);
    LDB(kt + 32, b1);
    CMP(a0f, b0);
    LDA(kt + 64, a0f);
    LDB(kt + 64, b0);
    CMP(a1f, b1);
  }
  LDA(kt + 32, a1f);
  LDB(kt + 32, b1);
  CMP(a0f, b0);
  CMP(a1f, b1);

  float* out = Out + (size_t)blockIdx.y * NN * COLS;
#pragma unroll
  for (int m = 0; m < 2; ++m)
#pragma unroll
    for (int cg = 0; cg < NCG; ++cg)
#pragma unroll
      for (int i = 0; i < 4; ++i)
        out[(size_t)(r0 + m * 16 + lg * 4 + i) * COLS + colg * (NCG * 16) + cg * 16 + l15] = acc[m][cg][i];
}

// ---------------- mid: B3p[k/32][c(64)][k&31] = relu(sum_p X2p @ We2 + be2) packed bf16
// 32-row tiles -> 256 blocks.
__global__ __launch_bounds__(256) void k_mid(const float* __restrict__ X2p,
                                             const float* __restrict__ We2,
                                             const float* __restrict__ be2,
                                             bf16* __restrict__ B3p, int KS) {
  __shared__ float X2s[32 * 128];
  __shared__ bf16 Os[64 * 40];
  int tid = threadIdx.x;
  int r0 = blockIdx.x * 32;
  for (int idx = tid; idx < 1024; idx += 256) {
    int r = idx >> 5, c4 = (idx & 31) * 4;
    float4 u = {0.f, 0.f, 0.f, 0.f};
    for (int p = 0; p < KS; ++p) {
      float4 v = *(const float4*)(X2p + (size_t)p * NN * 128 + (size_t)(r0 + r) * 128 + c4);
      u.x += v.x; u.y += v.y; u.z += v.z; u.w += v.w;
    }
    *(float4*)(&X2s[r * 128 + c4]) = u;
  }
  __syncthreads();
  int c = tid & 63, rb = tid >> 6;  // rows rb + 4k, k<8
  float acc[8];
  float b = be2[c];
#pragma unroll
  for (int k = 0; k < 8; ++k) acc[k] = b;
  for (int j = 0; j < 128; ++j) {
    float wv = We2[j * 64 + c];
#pragma unroll
    for (int k = 0; k < 8; ++k)
      acc[k] = fmaf(X2s[(rb + 4 * k) * 128 + j], wv, acc[k]);
  }
#pragma unroll
  for (int k = 0; k < 8; ++k) {
    float v = acc[k] > 0.f ? acc[k] : 0.f;
    Os[c * 40 + rb + 4 * k] = (bf16)v;
  }
  __syncthreads();
  int c2 = tid >> 2, h = tid & 3;  // 4 threads/col, 16B each
  const uint4* src = (const uint4*)(Os + c2 * 40 + h * 8);
  uint4* dst = (uint4*)(B3p + (size_t)(r0 / 32) * 64 * 32 + c2 * 32 + h * 8);
  dst[0] = src[0];
}

// ---------------- head: q = ((relu(relu([X4@Weo+beo, act]@Wc1+bc1)@Wc2+bc2))@Wq+bq)
__global__ __launch_bounds__(256) void k_head(const float* __restrict__ X4p,
                                              const float* __restrict__ actions,
                                              const float* __restrict__ Weo,
                                              const float* __restrict__ beo,
                                              const float* __restrict__ Wc1,
                                              const float* __restrict__ bc1,
                                              const float* __restrict__ Wc2,
                                              const float* __restrict__ bc2,
                                              const float* __restrict__ Wq,
                                              const float* __restrict__ bq,
                                              float* __restrict__ q, int KS) {
  __shared__ float X4s[32 * 65];
  __shared__ float hs[32 * 81];
  __shared__ float h1s[32 * 129];
  __shared__ float h2s[32 * 65];
  int tid = threadIdx.x;
  int r0 = blockIdx.x * 32;
  for (int idx = tid; idx < 2048; idx += 256) {
    int r = idx >> 6, c = idx & 63;
    float s = 0.f;
    for (int p = 0; p < KS; ++p)
      s += X4p[(size_t)p * NN * 64 + (size_t)(r0 + r) * 64 + c];
    X4s[r * 65 + c] = s;
  }
  for (int idx = tid; idx < 512; idx += 256) {
    int r = idx >> 4, a = idx & 15;
    hs[r * 81 + 64 + a] = actions[(r0 + r) * 16 + a];
  }
  __syncthreads();
  {  // emb = X4 @ Weo + beo
    int c = tid & 63, rb = tid >> 6;
    float acc[8];
    float b = beo[c];
#pragma unroll
    for (int k = 0; k < 8; ++k) acc[k] = b;
    for (int j = 0; j < 64; ++j) {
      float wv = Weo[j * 64 + c];
#pragma unroll
      for (int k = 0; k < 8; ++k)
        acc[k] = fmaf(X4s[(rb + 4 * k) * 65 + j], wv, acc[k]);
    }
#pragma unroll
    for (int k = 0; k < 8; ++k) hs[(rb + 4 * k) * 81 + c] = acc[k];
  }
  __syncthreads();
  {  // h1 = relu(h @ Wc1 + bc1)
    int c = tid & 127, rb = tid >> 7;
    float acc[16];
    float b = bc1[c];
#pragma unroll
    for (int k = 0; k < 16; ++k) acc[k] = b;
    for (int j = 0; j < 80; ++j) {
      float wv = Wc1[j * 128 + c];
#pragma unroll
      for (int k = 0; k < 16; ++k)
        acc[k] = fmaf(hs[(rb + 2 * k) * 81 + j], wv, acc[k]);
    }
#pragma unroll
    for (int k = 0; k < 16; ++k) {
      float v = acc[k] > 0.f ? acc[k] : 0.f;
      h1s[(rb + 2 * k) * 129 + c] = v;
    }
  }
  __syncthreads();
  {  // h2 = relu(h1 @ Wc2 + bc2)
    int c = tid & 63, rb = tid >> 6;
    float acc[8];
    float b = bc2[c];
#pragma unroll
    for (int k = 0; k < 8; ++k) acc[k] = b;
    for (int j = 0; j < 128; ++j) {
      float wv = Wc2[j * 64 + c];
#pragma unroll
      for (int k = 0; k < 8; ++k)
        acc[k] = fmaf(h1s[(rb + 4 * k) * 129 + j], wv, acc[k]);
    }
#pragma unroll
    for (int k = 0; k < 8; ++k) {
      float v = acc[k] > 0.f ? acc[k] : 0.f;
      h2s[(rb + 4 * k) * 65 + c] = v;
    }
  }
  __syncthreads();
  if (tid < 32) {
    float acc = bq[0];
    for (int j = 0; j < 64; ++j) acc = fmaf(h2s[tid * 65 + j], Wq[j], acc);
    q[r0 + tid] = acc;
  }
}

extern "C" void kernel_launch(void* const* d_in, const int* in_sizes, int n_in,
                              void* d_out, int out_size, void* d_ws, size_t ws_size,
                              hipStream_t stream) {
  const float* nodes = (const float*)d_in[0];
  const float* A = (const float*)d_in[2];
  const float* actions = (const float*)d_in[3];
  const float* We1 = (const float*)d_in[4];
  const float* be1 = (const float*)d_in[5];
  const float* We2 = (const float*)d_in[6];
  const float* be2 = (const float*)d_in[7];
  const float* Weo = (const float*)d_in[8];
  const float* beo = (const float*)d_in[9];
  const float* Wc1 = (const float*)d_in[10];
  const float* bc1 = (const float*)d_in[11];
  const float* Wc2 = (const float*)d_in[12];
  const float* bc2 = (const float*)d_in[13];
  const float* Wq = (const float*)d_in[14];
  const float* bq = (const float*)d_in[15];
  float* q = (float*)d_out;

  const size_t MB = 1ull << 20;
  int KS = 2;
  if (ws_size >= 3 * MB + 8 * 6 * MB) KS = 8;
  else if (ws_size >= 3 * MB + 4 * 6 * MB) KS = 4;

  char* ws = (char*)d_ws;
  bf16* B1p = (bf16*)(ws);                      // 2 MB packed [256][128][32]
  bf16* B3p = (bf16*)(ws + 2 * MB);             // 1 MB packed [256][64][32]
  float* X2p = (float*)(ws + 3 * MB);           // KS * 4 MB
  float* X4p = (float*)(ws + 3 * MB + (size_t)KS * 4 * MB);  // KS * 2 MB

  int KL = NN / KS;
  k_enc1<<<256, 256, 0, stream>>>(nodes, We1, be1, B1p);
  k_pass<4><<<dim3(128, KS), 256, 0, stream>>>(A, B1p, X2p, KL);
  k_mid<<<256, 256, 0, stream>>>(X2p, We2, be2, B3p, KS);
  k_pass<2><<<dim3(128, KS), 256, 0, stream>>>(A, B3p, X4p, KL);
  k_head<<<256, 256, 0, stream>>>(X4p, actions, Weo, beo, Wc1, bc1, Wc2, bc2, Wq, bq, q, KS);
}